// Round 1
// baseline (1303.498 us; speedup 1.0000x reference)
//
#include <hip/hip_runtime.h>

#define N_NODES 100000
#define HID 64
#define N_EDGES 1600000

// ---------------------------------------------------------------- gather
// x[i][:] = emb[node_id[i]][:]  (one float4 per thread)
__global__ void gather_kernel(const float* __restrict__ emb,
                              const int* __restrict__ nid,
                              float* __restrict__ x) {
    int i = blockIdx.x * blockDim.x + threadIdx.x;
    const int total = N_NODES * (HID / 4);
    if (i >= total) return;
    int row = i >> 4;   // / (HID/4)
    int c   = i & 15;
    int s   = nid[row];
    reinterpret_cast<float4*>(x)[row * 16 + c] =
        reinterpret_cast<const float4*>(emb)[s * 16 + c];
}

// ---------------------------------------------------------------- degree
__global__ void deg_kernel(const int* __restrict__ dst,
                           float* __restrict__ deg) {
    int e = blockIdx.x * blockDim.x + threadIdx.x;
    if (e < N_EDGES) atomicAdd(&deg[dst[e]], 1.0f);
}

// ---------------------------------------------------------------- scatter
// one wave (64 lanes) per edge; lane = feature column.
// gather read x[src][lane] is a coalesced 256B row; atomic adds coalesced.
__global__ void scatter_kernel(const int* __restrict__ src,
                               const int* __restrict__ dst,
                               const float* __restrict__ x,
                               float* __restrict__ agg) {
    int e = blockIdx.x * (blockDim.x >> 6) + (threadIdx.x >> 6);
    int lane = threadIdx.x & 63;
    if (e >= N_EDGES) return;
    int s = src[e];
    int d = dst[e];
    atomicAdd(&agg[d * HID + lane], x[s * HID + lane]);
}

// ---------------------------------------------------------------- combine
// out[i] = (agg[i]/max(deg,1)) @ Wl^T + x[i] @ Wr^T + b  (optional relu)
// Weights staged transposed in LDS: sW[k*64+o] = W[o*64+k] -> lane o reads
// consecutive addresses (conflict-free). Row values broadcast via __shfl.
__global__ void combine_kernel(const float* __restrict__ agg,
                               const float* __restrict__ deg,
                               const float* __restrict__ x,
                               const float* __restrict__ Wl,
                               const float* __restrict__ Wr,
                               const float* __restrict__ b,
                               float* __restrict__ out,
                               int relu) {
    __shared__ float sWl[HID * HID];
    __shared__ float sWr[HID * HID];
    __shared__ float sb[HID];
    for (int idx = threadIdx.x; idx < HID * HID; idx += blockDim.x) {
        int k = idx >> 6, o = idx & 63;
        sWl[idx] = Wl[o * HID + k];   // transposed store, conflict-free LDS write
        sWr[idx] = Wr[o * HID + k];
    }
    if (threadIdx.x < HID) sb[threadIdx.x] = b[threadIdx.x];
    __syncthreads();

    int lane = threadIdx.x & 63;
    int wpb = blockDim.x >> 6;
    int wid = blockIdx.x * wpb + (threadIdx.x >> 6);
    int stride = gridDim.x * wpb;
    for (int row = wid; row < N_NODES; row += stride) {
        float inv = 1.0f / fmaxf(deg[row], 1.0f);
        float a  = agg[row * HID + lane] * inv;
        float xv = x[row * HID + lane];
        float acc = sb[lane];
        #pragma unroll
        for (int k = 0; k < HID; ++k) {
            acc += __shfl(a, k)  * sWl[k * HID + lane];
            acc += __shfl(xv, k) * sWr[k * HID + lane];
        }
        if (relu) acc = fmaxf(acc, 0.0f);
        out[row * HID + lane] = acc;
    }
}

// ---------------------------------------------------------------- edge dot
// 16 lanes per edge, float4 per lane, xor-shuffle reduce within 16-lane group.
__global__ void edge_dot_kernel(const int* __restrict__ src,
                                const int* __restrict__ dst,
                                const float* __restrict__ h,
                                float* __restrict__ out) {
    int t = blockIdx.x * blockDim.x + threadIdx.x;
    int e = t >> 4;
    int c = t & 15;
    if (e >= N_EDGES) return;
    int a = src[e], bn = dst[e];
    float4 va = reinterpret_cast<const float4*>(h)[a * 16 + c];
    float4 vb = reinterpret_cast<const float4*>(h)[bn * 16 + c];
    float p = va.x * vb.x + va.y * vb.y + va.z * vb.z + va.w * vb.w;
    p += __shfl_xor(p, 1);
    p += __shfl_xor(p, 2);
    p += __shfl_xor(p, 4);
    p += __shfl_xor(p, 8);
    if (c == 0) out[e] = p;
}

extern "C" void kernel_launch(void* const* d_in, const int* in_sizes, int n_in,
                              void* d_out, int out_size, void* d_ws, size_t ws_size,
                              hipStream_t stream) {
    const float* emb = (const float*)d_in[0];
    const float* Wl1 = (const float*)d_in[1];
    const float* Wr1 = (const float*)d_in[2];
    const float* b1  = (const float*)d_in[3];
    const float* Wl2 = (const float*)d_in[4];
    const float* Wr2 = (const float*)d_in[5];
    const float* b2  = (const float*)d_in[6];
    const int*   nid = (const int*)d_in[7];
    const int*   ei  = (const int*)d_in[8];
    const int* esrc = ei;             // edge_index[0]
    const int* edst = ei + N_EDGES;   // edge_index[1]
    float* out = (float*)d_out;

    float* ws  = (float*)d_ws;
    float* x   = ws;                       // [N,64]  (reused as h2)
    float* h1  = ws + (size_t)N_NODES * HID;       // [N,64]
    float* agg = ws + (size_t)2 * N_NODES * HID;   // [N,64]
    float* deg = ws + (size_t)3 * N_NODES * HID;   // [N]

    // zero agg + deg (contiguous)
    hipMemsetAsync(agg, 0, ((size_t)N_NODES * HID + N_NODES) * sizeof(float), stream);

    // x = emb[node_id]
    gather_kernel<<<(N_NODES * 16 + 255) / 256, 256, 0, stream>>>(emb, nid, x);

    // degrees (shared by both layers)
    deg_kernel<<<(N_EDGES + 255) / 256, 256, 0, stream>>>(edst, deg);

    // ---- layer 1
    scatter_kernel<<<N_EDGES / 4, 256, 0, stream>>>(esrc, edst, x, agg);
    combine_kernel<<<1024, 256, 0, stream>>>(agg, deg, x, Wl1, Wr1, b1, h1, 1);

    // ---- layer 2
    hipMemsetAsync(agg, 0, (size_t)N_NODES * HID * sizeof(float), stream);
    scatter_kernel<<<N_EDGES / 4, 256, 0, stream>>>(esrc, edst, h1, agg);
    combine_kernel<<<1024, 256, 0, stream>>>(agg, deg, h1, Wl2, Wr2, b2, x /*h2*/, 0);

    // ---- edge classifier
    edge_dot_kernel<<<(N_EDGES * 16) / 256, 256, 0, stream>>>(esrc, edst, x, out);
}

// Round 2
// 982.744 us; speedup vs baseline: 1.3264x; 1.3264x over previous
//
#include <hip/hip_runtime.h>

#define N_NODES 100000
#define HID 64
#define N_EDGES 1600000
#define SCAN_B 1024
#define N_SCAN_BLOCKS ((N_NODES + SCAN_B - 1) / SCAN_B)   // 98

// ---------------------------------------------------------------- gather
__global__ void gather_kernel(const float* __restrict__ emb,
                              const int* __restrict__ nid,
                              float* __restrict__ x) {
    int i = blockIdx.x * blockDim.x + threadIdx.x;
    const int total = N_NODES * (HID / 4);
    if (i >= total) return;
    int row = i >> 4;
    int c   = i & 15;
    int s   = nid[row];
    reinterpret_cast<float4*>(x)[row * 16 + c] =
        reinterpret_cast<const float4*>(emb)[s * 16 + c];
}

// ---------------------------------------------------------------- degree (int)
__global__ void deg_kernel(const int* __restrict__ dst,
                           int* __restrict__ degi) {
    int e = blockIdx.x * blockDim.x + threadIdx.x;
    if (e < N_EDGES) atomicAdd(&degi[dst[e]], 1);
}

// ---------------------------------------------------------------- scan phase A
// per-block inclusive Hillis-Steele scan; write incl to row_start[i+1]; block sum out.
__global__ void scan_block(const int* __restrict__ degi,
                           int* __restrict__ row_start,
                           int* __restrict__ bsums) {
    __shared__ int s[SCAN_B];
    int gid = blockIdx.x * SCAN_B + threadIdx.x;
    int v = (gid < N_NODES) ? degi[gid] : 0;
    s[threadIdx.x] = v;
    __syncthreads();
    for (int off = 1; off < SCAN_B; off <<= 1) {
        int t = (threadIdx.x >= off) ? s[threadIdx.x - off] : 0;
        __syncthreads();
        s[threadIdx.x] += t;
        __syncthreads();
    }
    if (gid < N_NODES) row_start[gid + 1] = s[threadIdx.x];
    if (threadIdx.x == SCAN_B - 1) bsums[blockIdx.x] = s[SCAN_B - 1];
}

// ---------------------------------------------------------------- scan phase B
// single block: in-place exclusive scan of the 98 block sums.
__global__ void scan_bsums(int* __restrict__ bsums) {
    __shared__ int s[128];
    int v = (threadIdx.x < N_SCAN_BLOCKS) ? bsums[threadIdx.x] : 0;
    s[threadIdx.x] = v;
    __syncthreads();
    for (int off = 1; off < 128; off <<= 1) {
        int t = (threadIdx.x >= off) ? s[threadIdx.x - off] : 0;
        __syncthreads();
        s[threadIdx.x] += t;
        __syncthreads();
    }
    if (threadIdx.x < N_SCAN_BLOCKS) bsums[threadIdx.x] = s[threadIdx.x] - v; // exclusive
}

// ---------------------------------------------------------------- scan phase C
__global__ void scan_add(int* __restrict__ row_start,
                         const int* __restrict__ bsums) {
    int gid = blockIdx.x * SCAN_B + threadIdx.x;
    if (gid < N_NODES) row_start[gid + 1] += bsums[blockIdx.x];
    if (gid == 0) row_start[0] = 0;
}

// ---------------------------------------------------------------- CSR fill
__global__ void fill_adj(const int* __restrict__ src,
                         const int* __restrict__ dst,
                         const int* __restrict__ row_start,
                         int* __restrict__ cursor,
                         int* __restrict__ adj) {
    int e = blockIdx.x * blockDim.x + threadIdx.x;
    if (e >= N_EDGES) return;
    int d = dst[e];
    int pos = atomicAdd(&cursor[d], 1);
    adj[row_start[d] + pos] = src[e];
}

// ---------------------------------------------------------------- fused SAGE layer
// per-node pull aggregation + mean + dual GEMV (shfl broadcast, LDS-transposed W) + bias (+relu)
__global__ void sage_layer(const int* __restrict__ row_start,
                           const int* __restrict__ adj,
                           const int* __restrict__ degi,
                           const float* __restrict__ x,
                           const float* __restrict__ Wl,
                           const float* __restrict__ Wr,
                           const float* __restrict__ b,
                           float* __restrict__ out,
                           int relu) {
    __shared__ float sWl[HID * HID];
    __shared__ float sWr[HID * HID];
    __shared__ float sb[HID];
    for (int idx = threadIdx.x; idx < HID * HID; idx += blockDim.x) {
        int k = idx >> 6, o = idx & 63;
        sWl[idx] = Wl[o * HID + k];   // transposed: lane o reads k*64+o, conflict-free
        sWr[idx] = Wr[o * HID + k];
    }
    if (threadIdx.x < HID) sb[threadIdx.x] = b[threadIdx.x];
    __syncthreads();

    int lane = threadIdx.x & 63;
    int wpb = blockDim.x >> 6;
    int wid = blockIdx.x * wpb + (threadIdx.x >> 6);
    int stride = gridDim.x * wpb;
    for (int row = wid; row < N_NODES; row += stride) {
        int beg = row_start[row], end = row_start[row + 1];
        float acc = 0.0f;
        int j = beg;
        for (; j + 3 < end; j += 4) {          // 4 gathers in flight
            int s0 = adj[j], s1 = adj[j + 1], s2 = adj[j + 2], s3 = adj[j + 3];
            float v0 = x[(size_t)s0 * HID + lane];
            float v1 = x[(size_t)s1 * HID + lane];
            float v2 = x[(size_t)s2 * HID + lane];
            float v3 = x[(size_t)s3 * HID + lane];
            acc += v0; acc += v1; acc += v2; acc += v3;
        }
        for (; j < end; ++j) acc += x[(size_t)adj[j] * HID + lane];

        float d  = (float)degi[row];
        float a  = acc / fmaxf(d, 1.0f);
        float xv = x[(size_t)row * HID + lane];
        float o  = sb[lane];
        #pragma unroll
        for (int k = 0; k < HID; ++k) {
            o += __shfl(a, k)  * sWl[k * HID + lane];
            o += __shfl(xv, k) * sWr[k * HID + lane];
        }
        if (relu) o = fmaxf(o, 0.0f);
        out[(size_t)row * HID + lane] = o;
    }
}

// ---------------------------------------------------------------- edge dot
__global__ void edge_dot_kernel(const int* __restrict__ src,
                                const int* __restrict__ dst,
                                const float* __restrict__ h,
                                float* __restrict__ out) {
    int t = blockIdx.x * blockDim.x + threadIdx.x;
    int e = t >> 4;
    int c = t & 15;
    if (e >= N_EDGES) return;
    int a = src[e], bn = dst[e];
    float4 va = reinterpret_cast<const float4*>(h)[a * 16 + c];
    float4 vb = reinterpret_cast<const float4*>(h)[bn * 16 + c];
    float p = va.x * vb.x + va.y * vb.y + va.z * vb.z + va.w * vb.w;
    p += __shfl_xor(p, 1);
    p += __shfl_xor(p, 2);
    p += __shfl_xor(p, 4);
    p += __shfl_xor(p, 8);
    if (c == 0) out[e] = p;
}

extern "C" void kernel_launch(void* const* d_in, const int* in_sizes, int n_in,
                              void* d_out, int out_size, void* d_ws, size_t ws_size,
                              hipStream_t stream) {
    const float* emb = (const float*)d_in[0];
    const float* Wl1 = (const float*)d_in[1];
    const float* Wr1 = (const float*)d_in[2];
    const float* b1  = (const float*)d_in[3];
    const float* Wl2 = (const float*)d_in[4];
    const float* Wr2 = (const float*)d_in[5];
    const float* b2  = (const float*)d_in[6];
    const int*   nid = (const int*)d_in[7];
    const int*   ei  = (const int*)d_in[8];
    const int* esrc = ei;
    const int* edst = ei + N_EDGES;
    float* out = (float*)d_out;

    const size_t NH = (size_t)N_NODES * HID;
    float* ws = (float*)d_ws;
    float* x  = ws;            // [N,64] (reused as h2)
    float* h1 = ws + NH;       // [N,64]
    int* ib        = (int*)(ws + 2 * NH);
    int* degi      = ib;                          // [N]
    int* cursor    = ib + N_NODES;                // [N]  (adjacent to degi for one memset)
    int* row_start = ib + 2 * N_NODES;            // [N+1]
    int* adj       = ib + 3 * N_NODES + 64;       // [E]
    int* bsums     = adj + N_EDGES + 64;          // [128]

    // zero degi + cursor in one shot
    hipMemsetAsync(degi, 0, 2 * (size_t)N_NODES * sizeof(int), stream);

    // x = emb[node_id]
    gather_kernel<<<(N_NODES * 16 + 255) / 256, 256, 0, stream>>>(emb, nid, x);

    // ---- CSR build (shared by both layers)
    deg_kernel<<<(N_EDGES + 255) / 256, 256, 0, stream>>>(edst, degi);
    scan_block<<<N_SCAN_BLOCKS, SCAN_B, 0, stream>>>(degi, row_start, bsums);
    scan_bsums<<<1, 128, 0, stream>>>(bsums);
    scan_add<<<N_SCAN_BLOCKS, SCAN_B, 0, stream>>>(row_start, bsums);
    fill_adj<<<(N_EDGES + 255) / 256, 256, 0, stream>>>(esrc, edst, row_start, cursor, adj);

    // ---- layer 1 (fused aggregate + combine + relu)
    sage_layer<<<1024, 256, 0, stream>>>(row_start, adj, degi, x, Wl1, Wr1, b1, h1, 1);
    // ---- layer 2
    sage_layer<<<1024, 256, 0, stream>>>(row_start, adj, degi, h1, Wl2, Wr2, b2, x /*h2*/, 0);

    // ---- edge classifier
    edge_dot_kernel<<<((size_t)N_EDGES * 16 + 255) / 256, 256, 0, stream>>>(esrc, edst, x, out);
}